// Round 1
// baseline (73.558 us; speedup 1.0000x reference)
//
#include <hip/hip_runtime.h>
#include <hip/hip_bf16.h>

// Single-head causal attention, B=4096, T=64, C=128, H=64.
// One block per batch element; 4 waves; bf16 MFMA 16x16x32 for all matmuls.

typedef __bf16 bf16_t;
typedef __bf16 bf16x8 __attribute__((ext_vector_type(8)));
typedef __bf16 bf16x4 __attribute__((ext_vector_type(4)));
typedef float  f32x4  __attribute__((ext_vector_type(4)));

#define X_OFF   0        // 64 x 128 bf16, rowstride 256 B (reused as P after barrier 2)
#define Q_OFF   16384    // 64 x 64 bf16, rowstride 128 B
#define K_OFF   24576    // 64 x 64 bf16
#define VT_OFF  32768    // 64(h) x 64(t) bf16  (v stored transposed)
#define LDS_BYTES 40960

// XOR swizzle: spreads same-column accesses of 128/256B-stride rows across banks.
__device__ __forceinline__ int swz(int off, int row) { return off ^ ((row & 7) << 4); }

__global__ __launch_bounds__(256, 4)
void head_attn_kernel(const float* __restrict__ x,
                      const float* __restrict__ Wq,
                      const float* __restrict__ Wk,
                      const float* __restrict__ Wv,
                      float* __restrict__ out)
{
    __shared__ __align__(16) char smem[LDS_BYTES];
    const int b    = blockIdx.x;
    const int tid  = threadIdx.x;
    const int w    = tid >> 6;    // wave 0..3
    const int lane = tid & 63;
    const int l15  = lane & 15;
    const int lg   = lane >> 4;   // 16-lane group 0..3

    // ---------------- stage x[b] -> LDS as bf16 (swizzled) ----------------
    {
        const float4* xin = reinterpret_cast<const float4*>(x + (size_t)b * 8192);
        #pragma unroll
        for (int i = 0; i < 8; ++i) {
            int f4 = tid + i * 256;          // 2048 float4 total
            float4 v = xin[f4];
            int t  = f4 >> 5;                // 32 float4 per 128-elem row
            int c0 = (f4 & 31) << 2;
            bf16x4 h;
            h[0] = (bf16_t)v.x; h[1] = (bf16_t)v.y; h[2] = (bf16_t)v.z; h[3] = (bf16_t)v.w;
            *reinterpret_cast<bf16x4*>(smem + swz(X_OFF + t * 256 + c0 * 2, t)) = h;
        }
    }
    __syncthreads();

    // ---------------- QKV: [64 x 192] = x[64x128] @ Wqkv^T -----------------
    // wave w owns output cols [48w, 48w+48): tiles (rt 0..3) x (j 0..2)
    f32x4 acc[4][3];
    #pragma unroll
    for (int rt = 0; rt < 4; ++rt)
        #pragma unroll
        for (int j = 0; j < 3; ++j)
            acc[rt][j] = (f32x4){0.f, 0.f, 0.f, 0.f};

    #pragma unroll
    for (int ks = 0; ks < 4; ++ks) {
        bf16x8 bfrag[3];
        #pragma unroll
        for (int j = 0; j < 3; ++j) {
            int h = (w * 3 + j) * 16 + l15;              // 0..191
            const float* wr = (h < 64)  ? Wq + h * 128
                            : (h < 128) ? Wk + (h - 64) * 128
                                        : Wv + (h - 128) * 128;
            int c = ks * 32 + lg * 8;
            float4 w0 = *reinterpret_cast<const float4*>(wr + c);
            float4 w1 = *reinterpret_cast<const float4*>(wr + c + 4);
            bf16x8 bf;
            bf[0] = (bf16_t)w0.x; bf[1] = (bf16_t)w0.y; bf[2] = (bf16_t)w0.z; bf[3] = (bf16_t)w0.w;
            bf[4] = (bf16_t)w1.x; bf[5] = (bf16_t)w1.y; bf[6] = (bf16_t)w1.z; bf[7] = (bf16_t)w1.w;
            bfrag[j] = bf;
        }
        #pragma unroll
        for (int rt = 0; rt < 4; ++rt) {
            int t  = rt * 16 + l15;
            int c0 = ks * 32 + lg * 8;
            bf16x8 a = *reinterpret_cast<const bf16x8*>(smem + swz(X_OFF + t * 256 + c0 * 2, t));
            #pragma unroll
            for (int j = 0; j < 3; ++j)
                acc[rt][j] = __builtin_amdgcn_mfma_f32_16x16x32_bf16(a, bfrag[j], acc[rt][j], 0, 0, 0);
        }
    }

    // write q, k (row-major [t][h]) and v transposed [h][t] to LDS
    #pragma unroll
    for (int rt = 0; rt < 4; ++rt) {
        int t0 = rt * 16 + lg * 4;
        #pragma unroll
        for (int j = 0; j < 3; ++j) {
            int ctg = w * 3 + j;
            if (ctg < 4) {
                int h = ctg * 16 + l15;
                #pragma unroll
                for (int r = 0; r < 4; ++r)
                    *reinterpret_cast<bf16_t*>(smem + swz(Q_OFF + (t0 + r) * 128 + h * 2, t0 + r)) =
                        (bf16_t)acc[rt][j][r];
            } else if (ctg < 8) {
                int h = (ctg - 4) * 16 + l15;
                #pragma unroll
                for (int r = 0; r < 4; ++r)
                    *reinterpret_cast<bf16_t*>(smem + swz(K_OFF + (t0 + r) * 128 + h * 2, t0 + r)) =
                        (bf16_t)acc[rt][j][r];
            } else {
                int hv = (ctg - 8) * 16 + l15;
                bf16x4 pk;
                pk[0] = (bf16_t)acc[rt][j][0]; pk[1] = (bf16_t)acc[rt][j][1];
                pk[2] = (bf16_t)acc[rt][j][2]; pk[3] = (bf16_t)acc[rt][j][3];
                *reinterpret_cast<bf16x4*>(smem + swz(VT_OFF + hv * 128 + t0 * 2, hv)) = pk;
            }
        }
    }
    __syncthreads();

    // ---------------- wei = scale * q @ k^T, causal softmax -----------------
    // wave w owns rows [16w, 16w+16)
    f32x4 sacc[4];
    #pragma unroll
    for (int st = 0; st < 4; ++st) sacc[st] = (f32x4){0.f, 0.f, 0.f, 0.f};

    #pragma unroll
    for (int ks = 0; ks < 2; ++ks) {
        int h0 = ks * 32 + lg * 8;
        int tq = w * 16 + l15;
        bf16x8 a = *reinterpret_cast<const bf16x8*>(smem + swz(Q_OFF + tq * 128 + h0 * 2, tq));
        #pragma unroll
        for (int st = 0; st < 4; ++st) {
            int s = st * 16 + l15;
            bf16x8 kb = *reinterpret_cast<const bf16x8*>(smem + swz(K_OFF + s * 128 + h0 * 2, s));
            sacc[st] = __builtin_amdgcn_mfma_f32_16x16x32_bf16(a, kb, sacc[st], 0, 0, 0);
        }
    }

    // softmax rows (each row lives in one 16-lane group; 4 rows r per group)
    const int P_OFF = X_OFF + w * 2048;     // 16 x 64 bf16, rowstride 128 (reuses X)
    {
        const float scale = 0.125f;         // 64^-0.5
        #pragma unroll
        for (int r = 0; r < 4; ++r) {
            int t_loc = lg * 4 + r;
            int t     = w * 16 + t_loc;
            float pv[4];
            float m = -1e30f;
            #pragma unroll
            for (int st = 0; st < 4; ++st) {
                int s = st * 16 + l15;
                float v = sacc[st][r] * scale;
                if (s > t) v = -1e30f;       // causal mask
                pv[st] = v;
                m = fmaxf(m, v);
            }
            #pragma unroll
            for (int mk = 1; mk <= 8; mk <<= 1) m = fmaxf(m, __shfl_xor(m, mk, 64));
            float sum = 0.f;
            #pragma unroll
            for (int st = 0; st < 4; ++st) { pv[st] = __expf(pv[st] - m); sum += pv[st]; }
            #pragma unroll
            for (int mk = 1; mk <= 8; mk <<= 1) sum += __shfl_xor(sum, mk, 64);
            float inv = 1.0f / sum;
            #pragma unroll
            for (int st = 0; st < 4; ++st) {
                int s = st * 16 + l15;
                *reinterpret_cast<bf16_t*>(smem + swz(P_OFF + t_loc * 128 + s * 2, t_loc)) =
                    (bf16_t)(pv[st] * inv);
            }
        }
    }
    // same-wave LDS write->read: HW in-order, no barrier needed (wave-private region)

    // ---------------- out = P[16x64] @ v[64x64] ----------------------------
    f32x4 oacc[4];
    #pragma unroll
    for (int ht = 0; ht < 4; ++ht) oacc[ht] = (f32x4){0.f, 0.f, 0.f, 0.f};

    #pragma unroll
    for (int ks = 0; ks < 2; ++ks) {
        int s0 = ks * 32 + lg * 8;
        int tr = l15;
        bf16x8 a = *reinterpret_cast<const bf16x8*>(smem + swz(P_OFF + tr * 128 + s0 * 2, tr));
        #pragma unroll
        for (int ht = 0; ht < 4; ++ht) {
            int h = ht * 16 + l15;
            bf16x8 vb = *reinterpret_cast<const bf16x8*>(smem + swz(VT_OFF + h * 128 + s0 * 2, h));
            oacc[ht] = __builtin_amdgcn_mfma_f32_16x16x32_bf16(a, vb, oacc[ht], 0, 0, 0);
        }
    }

    float* ob = out + (size_t)b * 64 * 64;
    #pragma unroll
    for (int ht = 0; ht < 4; ++ht) {
        #pragma unroll
        for (int r = 0; r < 4; ++r) {
            int t = w * 16 + lg * 4 + r;
            int h = ht * 16 + l15;
            ob[t * 64 + h] = oacc[ht][r];
        }
    }
}

extern "C" void kernel_launch(void* const* d_in, const int* in_sizes, int n_in,
                              void* d_out, int out_size, void* d_ws, size_t ws_size,
                              hipStream_t stream) {
    const float* x  = (const float*)d_in[0];
    const float* Wq = (const float*)d_in[1];
    const float* Wk = (const float*)d_in[2];
    const float* Wv = (const float*)d_in[3];
    float* out = (float*)d_out;
    int B = in_sizes[0] / (64 * 128);   // 4096
    head_attn_kernel<<<B, 256, 0, stream>>>(x, Wq, Wk, Wv, out);
}